// Round 4
// baseline (103.682 us; speedup 1.0000x reference)
//
#include <hip/hip_runtime.h>
#include <math.h>

#define LL 1024
#define DD 640
#define KK 32
#define MM 64
#define THRESH 0.2f

// ws layout (float units)
#define NPROJ_OFF  0                        // [1024][64] node_proj + b_edge (backbone base)
#define NPROJC_OFF (NPROJ_OFF + LL * MM)    // [1024][64] node_proj + b_edge + W0 (contact base)
#define WRT_OFF    (NPROJC_OFF + LL * MM)   // ushort[64][32]: bf16 W_edge[2+k][m], m-major
#define W1_OFF     (WRT_OFF + 1024)         // 64 f32
#define MU_OFF     (W1_OFF + MM)            // 32 f32
#define NIS2_OFF   (MU_OFF + KK)            // 32 f32 : -1/(2 sigma^2)
#define XYZ4_OFF   (NIS2_OFF + KK)          // [1024][4] padded coords

typedef float f32x4_t __attribute__((ext_vector_type(4)));
typedef short bf16x8_t __attribute__((ext_vector_type(8)));

union FragU { unsigned int u[4]; bf16x8_t v; };

#if __has_builtin(__builtin_amdgcn_sqrtf)
#define FSQRT __builtin_amdgcn_sqrtf
#else
#define FSQRT sqrtf
#endif

// pack two fp32 into one VGPR of two bf16 (truncation; rbf magnitudes <= 1)
__device__ __forceinline__ unsigned int pack_bf(float hi, float lo) {
    return __builtin_amdgcn_perm(__float_as_uint(hi), __float_as_uint(lo), 0x07060302u);
}

__global__ __launch_bounds__(256) void prep_kernel(
    const float* __restrict__ S, const float* __restrict__ xyz,
    const float* __restrict__ rbf_mu, const float* __restrict__ rbf_sigma,
    const float* __restrict__ W_edge, const float* __restrict__ b_edge,
    const float* __restrict__ W_node, float* __restrict__ ws)
{
    __shared__ float red[4][2][64];
    const int b = blockIdx.x;
    const int t = threadIdx.x;
    if (b < LL / 2) {
        // node_proj: 2 rows/block; thread t: m = t&63, k-chunk c = t>>6
        const int m = t & 63;
        const int c = t >> 6;
        const int r0 = b * 2;
        float a0 = 0.f, a1 = 0.f;
        const int d0 = c * 160;
        #pragma unroll 4
        for (int dd = d0; dd < d0 + 160; dd += 4) {
            const float4 s0 = *(const float4*)(S + (size_t)r0 * DD + dd);
            const float4 s1 = *(const float4*)(S + (size_t)(r0 + 1) * DD + dd);
            const float w0 = W_node[(dd + 0) * MM + m];
            const float w1 = W_node[(dd + 1) * MM + m];
            const float w2 = W_node[(dd + 2) * MM + m];
            const float w3 = W_node[(dd + 3) * MM + m];
            a0 = fmaf(s0.x, w0, a0); a0 = fmaf(s0.y, w1, a0);
            a0 = fmaf(s0.z, w2, a0); a0 = fmaf(s0.w, w3, a0);
            a1 = fmaf(s1.x, w0, a1); a1 = fmaf(s1.y, w1, a1);
            a1 = fmaf(s1.z, w2, a1); a1 = fmaf(s1.w, w3, a1);
        }
        red[c][0][m] = a0;
        red[c][1][m] = a1;
        __syncthreads();
        if (t < 64) {
            const float be = b_edge[t];
            const float w0 = W_edge[t];    // W_edge row 0 (etype weight)
            const float v0 = ((red[0][0][t] + red[1][0][t]) + (red[2][0][t] + red[3][0][t])) + be;
            const float v1 = ((red[0][1][t] + red[1][1][t]) + (red[2][1][t] + red[3][1][t])) + be;
            ws[NPROJ_OFF  + (size_t)r0 * MM + t]       = v0;
            ws[NPROJ_OFF  + (size_t)(r0 + 1) * MM + t] = v1;
            ws[NPROJC_OFF + (size_t)r0 * MM + t]       = v0 + w0;
            ws[NPROJC_OFF + (size_t)(r0 + 1) * MM + t] = v1 + w0;
        }
    } else {
        // constants + padded xyz
        unsigned short* wrt = (unsigned short*)(ws + WRT_OFF);
        if (t < MM) ws[W1_OFF + t] = W_edge[MM + t];
        if (t < KK) {
            ws[MU_OFF + t] = rbf_mu[t];
            const float s = rbf_sigma[t];
            ws[NIS2_OFF + t] = -1.0f / (2.0f * s * s);
        }
        for (int idx = t; idx < KK * MM; idx += 256) {
            const int m = idx >> 5, k = idx & 31;
            unsigned int u = __float_as_uint(W_edge[(2 + k) * MM + m]);
            u = (u + 0x7fffu + ((u >> 16) & 1u)) >> 16;   // RNE to bf16
            wrt[idx] = (unsigned short)u;
        }
        for (int n = t; n < LL; n += 256) {
            float4 v;
            v.x = xyz[3 * n + 0]; v.y = xyz[3 * n + 1];
            v.z = xyz[3 * n + 2]; v.w = 0.0f;
            *(float4*)(ws + XYZ4_OFF + 4 * n) = v;
        }
    }
}

__global__ __launch_bounds__(256, 3) void edge_kernel(
    const float* __restrict__ P, const float* __restrict__ w_out,
    const float* __restrict__ ws, float* __restrict__ out)
{
    const int tid  = threadIdx.x;
    const int lane = tid & 63;
    const int wave = tid >> 6;
    const int quad = lane >> 4;
    const int col  = lane & 15;
    __shared__ float sred[4][3];

    const float* __restrict__ nproj  = ws + NPROJ_OFF;
    const float* __restrict__ nprojc = ws + NPROJC_OFF;
    const float4* __restrict__ xyz4  = (const float4*)(ws + XYZ4_OFF);
    const unsigned short* __restrict__ wrt = (const unsigned short*)(ws + WRT_OFF);

    // ---- persistent register state (pinned) ----
    FragU ar[4];                 // A[m = mt*16+col][k = quad*8+j] bf16
    float w1r[16], wvr[16];      // W1 / w_out at m = mt*16 + quad*4 + r
    float muj[8], nis2[8];
    #pragma unroll
    for (int mt = 0; mt < 4; ++mt) {
        const uint4 w = *(const uint4*)(wrt + (mt * 16 + col) * KK + quad * 8);
        ar[mt].u[0] = w.x; ar[mt].u[1] = w.y; ar[mt].u[2] = w.z; ar[mt].u[3] = w.w;
        const f32x4_t w1 = *(const f32x4_t*)(ws + W1_OFF + mt * 16 + quad * 4);
        const f32x4_t wo = *(const f32x4_t*)(w_out + mt * 16 + quad * 4);
        #pragma unroll
        for (int r = 0; r < 4; ++r) { w1r[mt * 4 + r] = w1[r]; wvr[mt * 4 + r] = wo[r]; }
    }
    #pragma unroll
    for (int j = 0; j < 8; ++j) {
        muj[j]  = ws[MU_OFF + quad * 8 + j];
        nis2[j] = ws[NIS2_OFF + quad * 8 + j];
    }
    // pin: un-rematerializable defs so the allocator keeps them live in VGPRs
    #pragma unroll
    for (int mt = 0; mt < 4; ++mt) {
        asm volatile("" : "+v"(ar[mt].u[0]), "+v"(ar[mt].u[1]),
                          "+v"(ar[mt].u[2]), "+v"(ar[mt].u[3]));
        asm volatile("" : "+v"(w1r[mt*4+0]), "+v"(w1r[mt*4+1]),
                          "+v"(w1r[mt*4+2]), "+v"(w1r[mt*4+3]));
        asm volatile("" : "+v"(wvr[mt*4+0]), "+v"(wvr[mt*4+1]),
                          "+v"(wvr[mt*4+2]), "+v"(wvr[mt*4+3]));
    }
    #pragma unroll
    for (int j = 0; j < 8; j += 4) {
        asm volatile("" : "+v"(muj[j]), "+v"(muj[j+1]), "+v"(muj[j+2]), "+v"(muj[j+3]));
        asm volatile("" : "+v"(nis2[j]), "+v"(nis2[j+1]), "+v"(nis2[j+2]), "+v"(nis2[j+3]));
    }

    // one row per block, longest-first (LPT): row i = blockIdx.x, len = 1023-i
    const int i = (int)blockIdx.x;
    const float4 xo = xyz4[i];
    const float xi0 = xo.x, xi1 = xo.y, xi2 = xo.z;
    float ax = 0.f, ay = 0.f, az = 0.f;
    const int len = (LL - 1) - i;

    for (int base = wave * 64; base < len; base += 256) {
        // own edge (mask + gated accumulation)
        const int jo = base + lane;
        const bool valid = jo < len;
        const int jc = valid ? (i + 1 + jo) : (LL - 1);
        const float p_own = P[(size_t)i * LL + jc];
        const float4 xj = xyz4[jc];
        const float rx = xj.x - xi0, ry = xj.y - xi1, rz = xj.z - xi2;
        const bool msk = valid && ((jo == 0) || ((jo >= 2) && (p_own > THRESH)));

        float res[4];
        #pragma unroll
        for (int ct = 0; ct < 4; ++ct) {
            const int jo_n = base + ct * 16 + col;
            int jc_n = i + 1 + jo_n;
            jc_n = (jc_n < LL) ? jc_n : (LL - 1);
            const float p_n = P[(size_t)i * LL + jc_n];
            const float4 xn = xyz4[jc_n];
            const float dx = xn.x - xi0, dy = xn.y - xi1, dz = xn.z - xi2;
            const float d_n = FSQRT(fmaf(dx, dx, fmaf(dy, dy, fmaf(dz, dz, 1e-12f))));
            const bool bb = (jo_n == 0);
            const float peff = bb ? 1.0f : p_n;
            const float* bp = bb ? nproj : nprojc;   // backbone: no W0; contact: +W0

            // B frag: rbf[k = quad*8+j][edge col]
            float r[8];
            #pragma unroll
            for (int j = 0; j < 8; ++j) {
                const float t0 = d_n - muj[j];
                r[j] = __expf(t0 * t0 * nis2[j]);
            }
            FragU bf;
            bf.u[0] = pack_bf(r[1], r[0]); bf.u[1] = pack_bf(r[3], r[2]);
            bf.u[2] = pack_bf(r[5], r[4]); bf.u[3] = pack_bf(r[7], r[6]);

            const float* npr = bp + (size_t)jc_n * MM;
            float g = 0.0f;
            #pragma unroll
            for (int mt = 0; mt < 4; ++mt) {
                f32x4_t c0 = *(const f32x4_t*)(npr + mt * 16 + quad * 4);
                c0[0] = fmaf(peff, w1r[mt*4+0], c0[0]);
                c0[1] = fmaf(peff, w1r[mt*4+1], c0[1]);
                c0[2] = fmaf(peff, w1r[mt*4+2], c0[2]);
                c0[3] = fmaf(peff, w1r[mt*4+3], c0[3]);
                c0 = __builtin_amdgcn_mfma_f32_16x16x32_bf16(ar[mt].v, bf.v, c0, 0, 0, 0);
                g = fmaf(fmaxf(c0[0], 0.f), wvr[mt*4+0], g);
                g = fmaf(fmaxf(c0[1], 0.f), wvr[mt*4+1], g);
                g = fmaf(fmaxf(c0[2], 0.f), wvr[mt*4+2], g);
                g = fmaf(fmaxf(c0[3], 0.f), wvr[mt*4+3], g);
            }
            g += __shfl_xor(g, 16, 64);
            g += __shfl_xor(g, 32, 64);
            res[ct] = g;
        }
        float gd = res[0];
        gd = (quad == 1) ? res[1] : gd;
        gd = (quad == 2) ? res[2] : gd;
        gd = (quad == 3) ? res[3] : gd;
        const float gate = msk ? (1.0f / (1.0f + __expf(-gd))) : 0.0f;
        ax = fmaf(gate, rx, ax);
        ay = fmaf(gate, ry, ay);
        az = fmaf(gate, rz, az);
    }

    #pragma unroll
    for (int off = 32; off > 0; off >>= 1) {
        ax += __shfl_down(ax, off, 64);
        ay += __shfl_down(ay, off, 64);
        az += __shfl_down(az, off, 64);
    }
    if (lane == 0) { sred[wave][0] = ax; sred[wave][1] = ay; sred[wave][2] = az; }
    __syncthreads();
    if (tid == 0) {
        const float tx = (sred[0][0] + sred[1][0]) + (sred[2][0] + sred[3][0]);
        const float ty = (sred[0][1] + sred[1][1]) + (sred[2][1] + sred[3][1]);
        const float tz = (sred[0][2] + sred[1][2]) + (sred[2][2] + sred[3][2]);
        out[i * 3 + 0] = xi0 + tx;
        out[i * 3 + 1] = xi1 + ty;
        out[i * 3 + 2] = xi2 + tz;
    }
}

extern "C" void kernel_launch(void* const* d_in, const int* in_sizes, int n_in,
                              void* d_out, int out_size, void* d_ws, size_t ws_size,
                              hipStream_t stream) {
    const float* S         = (const float*)d_in[0];
    const float* P         = (const float*)d_in[1];
    const float* xyz       = (const float*)d_in[2];
    const float* rbf_mu    = (const float*)d_in[3];
    const float* rbf_sigma = (const float*)d_in[4];
    const float* W_edge    = (const float*)d_in[5];
    const float* b_edge    = (const float*)d_in[6];
    const float* W_node    = (const float*)d_in[7];
    const float* w_out     = (const float*)d_in[8];
    float* out = (float*)d_out;
    float* ws  = (float*)d_ws;

    prep_kernel<<<LL / 2 + 1, 256, 0, stream>>>(S, xyz, rbf_mu, rbf_sigma,
                                                W_edge, b_edge, W_node, ws);
    edge_kernel<<<LL, 256, 0, stream>>>(P, w_out, ws, out);
}

// Round 5
// 99.855 us; speedup vs baseline: 1.0383x; 1.0383x over previous
//
#include <hip/hip_runtime.h>
#include <math.h>

#define LL 1024
#define DD 640
#define KK 32
#define MM 64
#define THRESH 0.2f

// ws layout (float units)
#define NPROJ_OFF  0                        // [1024][64] node_proj + b_edge (backbone base)
#define NPROJC_OFF (NPROJ_OFF + LL * MM)    // [1024][64] node_proj + b_edge + W0 (contact base)
#define WRT_OFF    (NPROJC_OFF + LL * MM)   // ushort[64][32]: bf16 W_edge[2+k][m], m-major
#define W1_OFF     (WRT_OFF + 1024)         // 64 f32
#define MU_OFF     (W1_OFF + MM)            // 32 f32
#define NIS2_OFF   (MU_OFF + KK)            // 32 f32 : -1/(2 sigma^2)
#define XYZ4_OFF   (NIS2_OFF + KK)          // [1024][4] padded coords

typedef float f32x4_t __attribute__((ext_vector_type(4)));
typedef short bf16x8_t __attribute__((ext_vector_type(8)));

union FragU { unsigned int u[4]; bf16x8_t v; };

#if __has_builtin(__builtin_amdgcn_sqrtf)
#define FSQRT __builtin_amdgcn_sqrtf
#else
#define FSQRT sqrtf
#endif

// pack two fp32 into one VGPR of two bf16 (truncation; inputs O(1))
__device__ __forceinline__ unsigned int pack_bf(float hi, float lo) {
    return __builtin_amdgcn_perm(__float_as_uint(hi), __float_as_uint(lo), 0x07060302u);
}

// node_proj = S(1024x640) @ W_node(640x64) via MFMA.
// 64 GEMM blocks x 4 waves: wave id -> row-tile id>>2 (16 rows), col-tile id&3 (16 cols).
// Block 64: constants repack + padded xyz table.
__global__ __launch_bounds__(256) void prep_gemm(
    const float* __restrict__ S, const float* __restrict__ xyz,
    const float* __restrict__ rbf_mu, const float* __restrict__ rbf_sigma,
    const float* __restrict__ W_edge, const float* __restrict__ b_edge,
    const float* __restrict__ W_node, float* __restrict__ ws)
{
    const int b = blockIdx.x;
    const int t = threadIdx.x;
    if (b < 64) {
        const int lane = t & 63;
        const int wave = t >> 6;
        const int id   = b * 4 + wave;        // 0..255
        const int r0   = (id >> 2) * 16;      // row tile
        const int n0   = (id & 3) * 16;       // col tile
        const int col  = lane & 15;
        const int quad = lane >> 4;

        f32x4_t acc = {0.f, 0.f, 0.f, 0.f};
        // A[m = lane&15][k = quad*8 + j] = S[r0+m][k]
        const float* arow = S + (size_t)(r0 + col) * DD + quad * 8;
        // B[k = quad*8 + j][n = lane&15] = W_node[k][n0+n]
        const float* bcol = W_node + (size_t)(quad * 8) * MM + n0 + col;

        #pragma unroll 2
        for (int ks = 0; ks < 20; ++ks) {
            const float4 a0 = *(const float4*)(arow + ks * 32);
            const float4 a1 = *(const float4*)(arow + ks * 32 + 4);
            FragU A;
            A.u[0] = pack_bf(a0.y, a0.x); A.u[1] = pack_bf(a0.w, a0.z);
            A.u[2] = pack_bf(a1.y, a1.x); A.u[3] = pack_bf(a1.w, a1.z);
            const float* bk = bcol + (size_t)ks * 32 * MM;
            const float b0 = bk[0 * MM], b1 = bk[1 * MM], b2 = bk[2 * MM], b3 = bk[3 * MM];
            const float b4 = bk[4 * MM], b5 = bk[5 * MM], b6 = bk[6 * MM], b7 = bk[7 * MM];
            FragU B;
            B.u[0] = pack_bf(b1, b0); B.u[1] = pack_bf(b3, b2);
            B.u[2] = pack_bf(b5, b4); B.u[3] = pack_bf(b7, b6);
            acc = __builtin_amdgcn_mfma_f32_16x16x32_bf16(A.v, B.v, acc, 0, 0, 0);
        }
        // C/D: row = r0 + quad*4 + r, col = n0 + (lane&15)
        const float bias = b_edge[n0 + col];
        const float w0   = W_edge[n0 + col];   // W_edge row 0 (etype weight)
        #pragma unroll
        for (int r = 0; r < 4; ++r) {
            const int row = r0 + quad * 4 + r;
            const float v = acc[r] + bias;
            ws[NPROJ_OFF  + (size_t)row * MM + n0 + col] = v;
            ws[NPROJC_OFF + (size_t)row * MM + n0 + col] = v + w0;
        }
    } else {
        // constants + padded xyz
        unsigned short* wrt = (unsigned short*)(ws + WRT_OFF);
        if (t < MM) ws[W1_OFF + t] = W_edge[MM + t];
        if (t < KK) {
            ws[MU_OFF + t] = rbf_mu[t];
            const float s = rbf_sigma[t];
            ws[NIS2_OFF + t] = -1.0f / (2.0f * s * s);
        }
        for (int idx = t; idx < KK * MM; idx += 256) {
            const int m = idx >> 5, k = idx & 31;
            unsigned int u = __float_as_uint(W_edge[(2 + k) * MM + m]);
            u = (u + 0x7fffu + ((u >> 16) & 1u)) >> 16;   // RNE to bf16
            wrt[idx] = (unsigned short)u;
        }
        for (int n = t; n < LL; n += 256) {
            float4 v;
            v.x = xyz[3 * n + 0]; v.y = xyz[3 * n + 1];
            v.z = xyz[3 * n + 2]; v.w = 0.0f;
            *(float4*)(ws + XYZ4_OFF + 4 * n) = v;
        }
    }
}

__global__ __launch_bounds__(256, 3) void edge_kernel(
    const float* __restrict__ P, const float* __restrict__ w_out,
    const float* __restrict__ ws, float* __restrict__ out)
{
    const int tid  = threadIdx.x;
    const int lane = tid & 63;
    const int wave = tid >> 6;
    const int quad = lane >> 4;
    const int col  = lane & 15;
    __shared__ float sred[4][3];

    const float* __restrict__ nproj  = ws + NPROJ_OFF;
    const float* __restrict__ nprojc = ws + NPROJC_OFF;
    const float4* __restrict__ xyz4  = (const float4*)(ws + XYZ4_OFF);
    const unsigned short* __restrict__ wrt = (const unsigned short*)(ws + WRT_OFF);

    // ---- persistent register state (pinned) ----
    FragU ar[4];                 // A[m = mt*16+col][k = quad*8+j] bf16
    float w1r[16], wvr[16];      // W1 / w_out at m = mt*16 + quad*4 + r
    float muj[8], nis2[8];
    #pragma unroll
    for (int mt = 0; mt < 4; ++mt) {
        const uint4 w = *(const uint4*)(wrt + (mt * 16 + col) * KK + quad * 8);
        ar[mt].u[0] = w.x; ar[mt].u[1] = w.y; ar[mt].u[2] = w.z; ar[mt].u[3] = w.w;
        const f32x4_t w1 = *(const f32x4_t*)(ws + W1_OFF + mt * 16 + quad * 4);
        const f32x4_t wo = *(const f32x4_t*)(w_out + mt * 16 + quad * 4);
        #pragma unroll
        for (int r = 0; r < 4; ++r) { w1r[mt * 4 + r] = w1[r]; wvr[mt * 4 + r] = wo[r]; }
    }
    #pragma unroll
    for (int j = 0; j < 8; ++j) {
        muj[j]  = ws[MU_OFF + quad * 8 + j];
        nis2[j] = ws[NIS2_OFF + quad * 8 + j];
    }
    #pragma unroll
    for (int mt = 0; mt < 4; ++mt) {
        asm volatile("" : "+v"(ar[mt].u[0]), "+v"(ar[mt].u[1]),
                          "+v"(ar[mt].u[2]), "+v"(ar[mt].u[3]));
        asm volatile("" : "+v"(w1r[mt*4+0]), "+v"(w1r[mt*4+1]),
                          "+v"(w1r[mt*4+2]), "+v"(w1r[mt*4+3]));
        asm volatile("" : "+v"(wvr[mt*4+0]), "+v"(wvr[mt*4+1]),
                          "+v"(wvr[mt*4+2]), "+v"(wvr[mt*4+3]));
    }
    #pragma unroll
    for (int j = 0; j < 8; j += 4) {
        asm volatile("" : "+v"(muj[j]), "+v"(muj[j+1]), "+v"(muj[j+2]), "+v"(muj[j+3]));
        asm volatile("" : "+v"(nis2[j]), "+v"(nis2[j+1]), "+v"(nis2[j+2]), "+v"(nis2[j+3]));
    }

    // one row per block, longest-first (LPT): row i = blockIdx.x, len = 1023-i
    const int i = (int)blockIdx.x;
    const float4 xo = xyz4[i];
    const float xi0 = xo.x, xi1 = xo.y, xi2 = xo.z;
    float ax = 0.f, ay = 0.f, az = 0.f;
    const int len = (LL - 1) - i;

    for (int base = wave * 64; base < len; base += 256) {
        const int jo = base + lane;
        const bool valid = jo < len;
        const int jc = valid ? (i + 1 + jo) : (LL - 1);
        const float p_own = P[(size_t)i * LL + jc];
        const float4 xj = xyz4[jc];
        const float rx = xj.x - xi0, ry = xj.y - xi1, rz = xj.z - xi2;
        const bool msk = valid && ((jo == 0) || ((jo >= 2) && (p_own > THRESH)));

        float res[4];
        #pragma unroll
        for (int ct = 0; ct < 4; ++ct) {
            const int jo_n = base + ct * 16 + col;
            int jc_n = i + 1 + jo_n;
            jc_n = (jc_n < LL) ? jc_n : (LL - 1);
            const float p_n = P[(size_t)i * LL + jc_n];
            const float4 xn = xyz4[jc_n];
            const float dx = xn.x - xi0, dy = xn.y - xi1, dz = xn.z - xi2;
            const float d_n = FSQRT(fmaf(dx, dx, fmaf(dy, dy, fmaf(dz, dz, 1e-12f))));
            const bool bb = (jo_n == 0);
            const float peff = bb ? 1.0f : p_n;
            const float* bp = bb ? nproj : nprojc;

            float r[8];
            #pragma unroll
            for (int j = 0; j < 8; ++j) {
                const float t0 = d_n - muj[j];
                r[j] = __expf(t0 * t0 * nis2[j]);
            }
            FragU bf;
            bf.u[0] = pack_bf(r[1], r[0]); bf.u[1] = pack_bf(r[3], r[2]);
            bf.u[2] = pack_bf(r[5], r[4]); bf.u[3] = pack_bf(r[7], r[6]);

            const float* npr = bp + (size_t)jc_n * MM;
            float g = 0.0f;
            #pragma unroll
            for (int mt = 0; mt < 4; ++mt) {
                f32x4_t c0 = *(const f32x4_t*)(npr + mt * 16 + quad * 4);
                c0[0] = fmaf(peff, w1r[mt*4+0], c0[0]);
                c0[1] = fmaf(peff, w1r[mt*4+1], c0[1]);
                c0[2] = fmaf(peff, w1r[mt*4+2], c0[2]);
                c0[3] = fmaf(peff, w1r[mt*4+3], c0[3]);
                c0 = __builtin_amdgcn_mfma_f32_16x16x32_bf16(ar[mt].v, bf.v, c0, 0, 0, 0);
                g = fmaf(fmaxf(c0[0], 0.f), wvr[mt*4+0], g);
                g = fmaf(fmaxf(c0[1], 0.f), wvr[mt*4+1], g);
                g = fmaf(fmaxf(c0[2], 0.f), wvr[mt*4+2], g);
                g = fmaf(fmaxf(c0[3], 0.f), wvr[mt*4+3], g);
            }
            g += __shfl_xor(g, 16, 64);
            g += __shfl_xor(g, 32, 64);
            res[ct] = g;
        }
        float gd = res[0];
        gd = (quad == 1) ? res[1] : gd;
        gd = (quad == 2) ? res[2] : gd;
        gd = (quad == 3) ? res[3] : gd;
        const float gate = msk ? (1.0f / (1.0f + __expf(-gd))) : 0.0f;
        ax = fmaf(gate, rx, ax);
        ay = fmaf(gate, ry, ay);
        az = fmaf(gate, rz, az);
    }

    #pragma unroll
    for (int off = 32; off > 0; off >>= 1) {
        ax += __shfl_down(ax, off, 64);
        ay += __shfl_down(ay, off, 64);
        az += __shfl_down(az, off, 64);
    }
    if (lane == 0) { sred[wave][0] = ax; sred[wave][1] = ay; sred[wave][2] = az; }
    __syncthreads();
    if (tid == 0) {
        const float tx = (sred[0][0] + sred[1][0]) + (sred[2][0] + sred[3][0]);
        const float ty = (sred[0][1] + sred[1][1]) + (sred[2][1] + sred[3][1]);
        const float tz = (sred[0][2] + sred[1][2]) + (sred[2][2] + sred[3][2]);
        out[i * 3 + 0] = xi0 + tx;
        out[i * 3 + 1] = xi1 + ty;
        out[i * 3 + 2] = xi2 + tz;
    }
}

extern "C" void kernel_launch(void* const* d_in, const int* in_sizes, int n_in,
                              void* d_out, int out_size, void* d_ws, size_t ws_size,
                              hipStream_t stream) {
    const float* S         = (const float*)d_in[0];
    const float* P         = (const float*)d_in[1];
    const float* xyz       = (const float*)d_in[2];
    const float* rbf_mu    = (const float*)d_in[3];
    const float* rbf_sigma = (const float*)d_in[4];
    const float* W_edge    = (const float*)d_in[5];
    const float* b_edge    = (const float*)d_in[6];
    const float* W_node    = (const float*)d_in[7];
    const float* w_out     = (const float*)d_in[8];
    float* out = (float*)d_out;
    float* ws  = (float*)d_ws;

    prep_gemm<<<65, 256, 0, stream>>>(S, xyz, rbf_mu, rbf_sigma,
                                      W_edge, b_edge, W_node, ws);
    edge_kernel<<<LL, 256, 0, stream>>>(P, w_out, ws, out);
}